// Round 8
// baseline (640.244 us; speedup 1.0000x reference)
//
#include <hip/hip_runtime.h>
#include <hip/hip_bf16.h>
#include <math.h>

#define T_LEN 2048
#define B_SZ  2
#define C_DIM 1024
#define H_NUM 16
#define D_HEAD 64
#define F_DIM 4096
#define NT    (T_LEN * B_SZ)   // 4096 tokens
#define BH    (B_SZ * H_NUM)   // 32 head-batches
#define C3    (3 * C_DIM)      // 3072

typedef __attribute__((ext_vector_type(8))) short short8v;  // 8 bf16 = 1 MFMA operand frag
typedef __attribute__((ext_vector_type(4))) float f32x4;    // 16x16 MFMA C/D frag
typedef __hip_bfloat16 bf16;

__device__ __forceinline__ float bf2f(bf16 v) { return __bfloat162float(v); }
__device__ __forceinline__ bf16  f2bf(float f) { return __float2bfloat16(f); }
__device__ __forceinline__ short f2bfs(float f) { bf16 h = __float2bfloat16(f); return *(short*)&h; }
__device__ __forceinline__ void split2(float v, short& h, short& l) {
    bf16 hb = __float2bfloat16(v);
    bf16 lb = __float2bfloat16(v - __bfloat162float(hb));
    h = *(short*)&hb; l = *(short*)&lb;
}
__device__ __forceinline__ f32x4 mfma16(short8v a, short8v b, f32x4 c) {
    return __builtin_amdgcn_mfma_f32_16x16x32_bf16(a, b, c, 0, 0, 0);
}
// async global->LDS, 16B per lane; LDS dest = wave-uniform base + lane*16
__device__ __forceinline__ void async16(const void* g, void* lds) {
    __builtin_amdgcn_global_load_lds(
        (const __attribute__((address_space(1))) void*)g,
        (__attribute__((address_space(3))) void*)lds, 16, 0, 0);
}

// ---------------------------------------------------------------- block sum
__device__ __forceinline__ float block_sum_256(float val, float* sred) {
#pragma unroll
    for (int off = 32; off > 0; off >>= 1)
        val += __shfl_down(val, off, 64);
    int lane = threadIdx.x & 63;
    int wid  = threadIdx.x >> 6;
    if (lane == 0) sred[wid] = val;
    __syncthreads();
    float r = sred[0] + sred[1] + sred[2] + sred[3];
    __syncthreads();
    return r;
}

// ---------------------------------------------------------------- fp32 -> bf16 hi/lo split (weights)
__global__ __launch_bounds__(256) void split_kernel(const float* __restrict__ src,
                                                    bf16* __restrict__ hi, bf16* __restrict__ lo) {
    int i = blockIdx.x * 256 + threadIdx.x;   // one float4 per thread; n % 1024 == 0
    float4 v = ((const float4*)src)[i];
    short4 hv, lv;
    split2(v.x, hv.x, lv.x); split2(v.y, hv.y, lv.y);
    split2(v.z, hv.z, lv.z); split2(v.w, hv.w, lv.w);
    ((short4*)hi)[i] = hv;
    ((short4*)lo)[i] = lv;
}

// ---------------------------------------------------------------- LayerNorm -> bf16 hi/lo
__global__ __launch_bounds__(256) void ln_split_kernel(const float* __restrict__ x,
                                                       const float* __restrict__ g,
                                                       const float* __restrict__ b,
                                                       bf16* __restrict__ oh, bf16* __restrict__ ol) {
    __shared__ float sred[4];
    int row = blockIdx.x;
    int tid = threadIdx.x;
    const float* xr = x + (size_t)row * C_DIM;
    float4 xv = *(const float4*)(xr + tid * 4);
    float s = xv.x + xv.y + xv.z + xv.w;
    s = block_sum_256(s, sred);
    float mu = s * (1.0f / C_DIM);
    float d0 = xv.x - mu, d1 = xv.y - mu, d2 = xv.z - mu, d3 = xv.w - mu;
    float vs = d0 * d0 + d1 * d1 + d2 * d2 + d3 * d3;
    vs = block_sum_256(vs, sred);
    float rstd = rsqrtf(vs * (1.0f / C_DIM) + 1e-5f);
    float4 gv = *(const float4*)(g + tid * 4);
    float4 bv = *(const float4*)(b + tid * 4);
    float y0 = d0 * rstd * gv.x + bv.x, y1 = d1 * rstd * gv.y + bv.y;
    float y2 = d2 * rstd * gv.z + bv.z, y3 = d3 * rstd * gv.w + bv.w;
    short4 hv, lv;
    split2(y0, hv.x, lv.x); split2(y1, hv.y, lv.y);
    split2(y2, hv.z, lv.z); split2(y3, hv.w, lv.w);
    size_t base = (size_t)row * C_DIM / 4 + tid;
    ((short4*)oh)[base] = hv;
    ((short4*)ol)[base] = lv;
}

// ---------------------------------------------------------------- split-bf16 MFMA GEMM (NT)
// C[m,n] = sum_k A[m,k]*Bw[n,k] + bias[n] (+gelu | +res). acc = Ah*Bh + Ah*Bl (+ Al*Bh if ASPLIT).
// 128x128 tile, BK=32, 4 waves (2x2), per-wave 64x64 = 4x4 frags of 16x16x32.
// LDS logical layout: position (row, chunk c) holds global 16B-chunk c ^ ((row>>1)&3).
// Staged via global_load_lds: linear LDS dest (seg*1024 + lane*16), per-lane
// inverse-swizzled GLOBAL source (rule: source permutation == read permutation).
// Frag read at chunk pos g4 ^ ((row>>1)&3) -> retrieves global chunk g4. <=2-way banks.
template <int EPI, bool ASPLIT, bool OUTBF16>
__global__ __launch_bounds__(256) void gemm_bf16(const bf16* __restrict__ Ah, const bf16* __restrict__ Al,
                                                 const bf16* __restrict__ Bh, const bf16* __restrict__ Bl,
                                                 const float* __restrict__ bias, const float* __restrict__ res,
                                                 float* __restrict__ Cf, bf16* __restrict__ Cb,
                                                 int N, int K) {
    __shared__ __align__(16) short LAh[128 * 32];
    __shared__ __align__(16) short LBh[128 * 32];
    __shared__ __align__(16) short LBl[128 * 32];
    __shared__ __align__(16) short LAl[ASPLIT ? 128 * 32 : 8];
    char* LAhB = (char*)LAh; char* LBhB = (char*)LBh;
    char* LBlB = (char*)LBl; char* LAlB = (char*)LAl;

    int tid = threadIdx.x;
    int w = tid >> 6, l = tid & 63;
    int c = l & 15, g4 = l >> 4;
    int wm = w >> 1, wn = w & 1;
    int bn = blockIdx.x, bm = blockIdx.y;

    f32x4 acc[4][4];
#pragma unroll
    for (int i = 0; i < 4; i++)
#pragma unroll
        for (int j = 0; j < 4; j++) acc[i][j] = (f32x4){0.f, 0.f, 0.f, 0.f};

    // staging tables: buffer order {Ah, Bh, Bl, Al}; wave-uniform LDS segment bases
    const bf16* gB[4];
    gB[0] = Ah + (size_t)bm * 128 * K;
    gB[1] = Bh + (size_t)bn * 128 * K;
    gB[2] = Bl + (size_t)bn * 128 * K;
    gB[3] = ASPLIT ? (Al + (size_t)bm * 128 * K) : gB[0];
    char* lB[4] = {LAhB, LBhB, LBlB, LAlB};
    const int NSEG = (ASPLIT ? 4 : 3) * 8;   // 8 segments of 1KB per 8KB buffer
    int lr4 = l >> 2, lc4 = l & 3;           // lane -> (row-in-seg, chunk)

    auto STAGE = [&](int kt) {
#pragma unroll
        for (int sidx = w; sidx < NSEG; sidx += 4) {
            int bsel = sidx >> 3, seg = sidx & 7;
            int r = seg * 16 + lr4;
            int cs = lc4 ^ ((r >> 1) & 3);                     // inverse-swizzled source chunk
            const bf16* g = gB[bsel] + (size_t)r * K + kt + cs * 8;
            async16(g, lB[bsel] + seg * 1024);                 // + lane*16 implicit
        }
    };

    for (int kt = 0; kt < K; kt += 32) {
        STAGE(kt);
        __syncthreads();          // drains vmcnt -> LDS tile ready for all waves

        short8v fah[4], fal[4], fbh[4], fbl[4];
#pragma unroll
        for (int i = 0; i < 4; i++) {
            int row = wm * 64 + i * 16 + c;
            int off = row * 64 + 16 * (g4 ^ ((row >> 1) & 3));
            fah[i] = *(const short8v*)(LAhB + off);
            if (ASPLIT) fal[i] = *(const short8v*)(LAlB + off);
        }
#pragma unroll
        for (int j = 0; j < 4; j++) {
            int row = wn * 64 + j * 16 + c;
            int off = row * 64 + 16 * (g4 ^ ((row >> 1) & 3));
            fbh[j] = *(const short8v*)(LBhB + off);
            fbl[j] = *(const short8v*)(LBlB + off);
        }
#pragma unroll
        for (int i = 0; i < 4; i++)
#pragma unroll
            for (int j = 0; j < 4; j++) {
                f32x4 t = acc[i][j];
                t = mfma16(fah[i], fbl[j], t);
                if (ASPLIT) t = mfma16(fal[i], fbh[j], t);
                t = mfma16(fah[i], fbh[j], t);
                acc[i][j] = t;
            }
        __syncthreads();          // all frag reads done before next STAGE overwrites
    }

#pragma unroll
    for (int i = 0; i < 4; i++)
#pragma unroll
        for (int j = 0; j < 4; j++) {
            int colg = bn * 128 + wn * 64 + j * 16 + c;
            float bv = bias[colg];
#pragma unroll
            for (int r = 0; r < 4; r++) {
                int rowg = bm * 128 + wm * 64 + i * 16 + g4 * 4 + r;
                float v = acc[i][j][r] + bv;
                if (EPI == 1) {
                    float t = tanhf(0.7978845608028654f * (v + 0.044715f * v * v * v));
                    v = 0.5f * v * (1.0f + t);
                } else if (EPI == 2) {
                    v += res[(size_t)rowg * N + colg];
                }
                if (OUTBF16) Cb[(size_t)rowg * N + colg] = f2bf(v);
                else         Cf[(size_t)rowg * N + colg] = v;
            }
        }
}

// ---------------------------------------------------------------- RoPE (q,k) from bf16 qkv
__global__ __launch_bounds__(256) void rope_kernel(const bf16* __restrict__ qkv,
                                                   bf16* __restrict__ Q, bf16* __restrict__ K) {
    int idx = blockIdx.x * 256 + threadIdx.x;  // BH * T * 32
    int d  = idx & 31;
    int t  = (idx >> 5) & (T_LEN - 1);
    int bh = idx >> 16;
    int b  = bh >> 4;
    int h  = bh & 15;
    size_t row = (size_t)(t * B_SZ + b) * C3 + h * D_HEAD + d;
    float q0 = bf2f(qkv[row]),          q1 = bf2f(qkv[row + 32]);
    float k0 = bf2f(qkv[row + C_DIM]),  k1 = bf2f(qkv[row + C_DIM + 32]);
    q0 *= 0.125f; q1 *= 0.125f;               // D^-0.5
    float theta = exp2f((float)d * (-13.287712379549449f / 32.0f));  // 10000^(-d/32)
    float ang = (float)t * theta;
    float sn, cs;
    sincosf(ang, &sn, &cs);
    size_t ob = ((size_t)bh * T_LEN + t) * D_HEAD + d;
    Q[ob]      = f2bf(cs * q0 - sn * q1);
    Q[ob + 32] = f2bf(cs * q1 + sn * q0);
    K[ob]      = f2bf(cs * k0 - sn * k1);
    K[ob + 32] = f2bf(cs * k1 + sn * k0);
}

// ---------------------------------------------------------------- V transpose: qkv v-part -> Vt (BH, D, T)
// LDS elem(t,d) @ byte t*128 + 16*((d>>3)^((t>>3)&7)) + 2*(d&7): both phases <=2-way banks.
__global__ __launch_bounds__(256) void vt_kernel(const bf16* __restrict__ qkv, bf16* __restrict__ Vt) {
    __shared__ __align__(16) short L[64 * 64];
    char* LB = (char*)L;
    int qt = blockIdx.x, bh = blockIdx.y;
    int b = bh >> 4, h = bh & 15;
    int tid = threadIdx.x;
    int t0 = qt * 64;
#pragma unroll
    for (int e = 0; e < 2; e++) {
        int t = (tid >> 3) + e * 32, dc = tid & 7;
        short8v v = *(const short8v*)(qkv + (size_t)((t0 + t) * B_SZ + b) * C3 + 2 * C_DIM + h * 64 + dc * 8);
        *(short8v*)(LB + t * 128 + 16 * (dc ^ ((t >> 3) & 7))) = v;
    }
    __syncthreads();
    int d = tid & 63, tcb = tid >> 6;   // 16 t per thread
    short8v v0, v1;
#pragma unroll
    for (int i = 0; i < 8; i++) {
        int t = tcb * 16 + i;
        v0[i] = *(const short*)(LB + t * 128 + 16 * ((d >> 3) ^ ((t >> 3) & 7)) + 2 * (d & 7));
    }
#pragma unroll
    for (int i = 0; i < 8; i++) {
        int t = tcb * 16 + 8 + i;
        v1[i] = *(const short*)(LB + t * 128 + 16 * ((d >> 3) ^ ((t >> 3) & 7)) + 2 * (d & 7));
    }
    bf16* op = Vt + ((size_t)bh * 64 + d) * T_LEN + t0 + tcb * 16;
    *(short8v*)(op)     = v0;
    *(short8v*)(op + 8) = v1;
}

// ---------------------------------------------------------------- causal flash attention, bf16 MFMA
// grid (T/64, BH), 4 waves. Wave w: 16 q-rows. KV tile 64. Q in regs; K/Vt staged in swizzled LDS.
// LPT balance: qt = gridDim.x-1-blockIdx.x so 32-tile blocks dispatch FIRST (kills the
// sparse tail that capped occupancy at 13.7%).
// K elem(kv,d): byte kv*128 + 16*((d>>3)^(kv&7)) + 2*(d&7)
// Vt elem(d,kv): byte d*128 + 16*((kv>>3)^(d&7)) + 2*(kv&7)
// Ps elem(q,kv) per wave: byte q*128 + 16*((kv>>3)^(q&7)) + 2*(kv&7)
__global__ __launch_bounds__(256) void attn_kernel(const bf16* __restrict__ Qg, const bf16* __restrict__ Kg,
                                                   const bf16* __restrict__ Vt,
                                                   bf16* __restrict__ Ohi, bf16* __restrict__ Olo) {
    __shared__ __align__(16) short Kl[64 * 64];
    __shared__ __align__(16) short Vl[64 * 64];
    __shared__ __align__(16) short Ps[4 * 16 * 64];
    char* KlB = (char*)Kl; char* VlB = (char*)Vl;
    int qt = gridDim.x - 1 - blockIdx.x;     // LPT: heaviest q-tiles first
    int bh = blockIdx.y;
    int tid = threadIdx.x;
    int w = tid >> 6, l = tid & 63;
    int c = l & 15, g4 = l >> 4;
    char* PsB = (char*)Ps + w * 2048;

    // Q fragments (2 k-steps of 32 over D=64), direct from global
    int q0 = qt * 64 + w * 16;
    const bf16* Qb = Qg + ((size_t)bh * T_LEN + q0 + c) * 64 + g4 * 8;
    short8v qf0 = *(const short8v*)(Qb);
    short8v qf1 = *(const short8v*)(Qb + 32);

    f32x4 oacc[4];
    float m_r[4], l_r[4];
#pragma unroll
    for (int i = 0; i < 4; i++) { oacc[i] = (f32x4){0.f,0.f,0.f,0.f}; m_r[i] = -1e30f; l_r[i] = 0.f; }

    int skv = tid >> 3, sc8 = tid & 7;      // staging coords
    for (int kt = 0; kt <= qt; kt++) {
        int kv0 = kt * 64;
        // ---- stage K tile + Vt tile (reg -> swizzled LDS)
        short8v kreg[2], vreg[2];
#pragma unroll
        for (int e = 0; e < 2; e++) {
            int rkv = skv + e * 32;
            kreg[e] = *(const short8v*)(Kg + ((size_t)bh * T_LEN + kv0 + rkv) * 64 + sc8 * 8);
            vreg[e] = *(const short8v*)(Vt + ((size_t)bh * 64 + rkv) * T_LEN + kv0 + sc8 * 8);
        }
        __syncthreads();   // prev tile's LDS reads done
#pragma unroll
        for (int e = 0; e < 2; e++) {
            int rkv = skv + e * 32;
            *(short8v*)(KlB + rkv * 128 + 16 * (sc8 ^ (rkv & 7))) = kreg[e];
            *(short8v*)(VlB + rkv * 128 + 16 * (sc8 ^ (rkv & 7))) = vreg[e];
        }
        __syncthreads();

        // ---- scores S = Q K^T : 4 kv-frags x 2 d-steps
        f32x4 s[4];
#pragma unroll
        for (int j = 0; j < 4; j++) s[j] = (f32x4){0.f,0.f,0.f,0.f};
#pragma unroll
        for (int j = 0; j < 4; j++) {
            int row = j * 16 + c;
            short8v kb0 = *(const short8v*)(KlB + row * 128 + 16 * ((g4)     ^ (row & 7)));
            short8v kb1 = *(const short8v*)(KlB + row * 128 + 16 * ((4 + g4) ^ (row & 7)));
            s[j] = mfma16(qf0, kb0, s[j]);
            s[j] = mfma16(qf1, kb1, s[j]);
        }
        if (kt == qt) {   // causal mask within diagonal tile
#pragma unroll
            for (int j = 0; j < 4; j++)
#pragma unroll
                for (int r = 0; r < 4; r++)
                    if (j * 16 + c > w * 16 + g4 * 4 + r) s[j][r] = -1e30f;
        }

        // ---- online softmax (rows r; 16 cols per frag across lanes c)
#pragma unroll
        for (int r = 0; r < 4; r++) {
            float tm = fmaxf(fmaxf(s[0][r], s[1][r]), fmaxf(s[2][r], s[3][r]));
#pragma unroll
            for (int mk = 1; mk < 16; mk <<= 1) tm = fmaxf(tm, __shfl_xor(tm, mk, 64));
            float mnew = fmaxf(m_r[r], tm);
            float sc = __expf(m_r[r] - mnew);
            int q = g4 * 4 + r;
            float rs = 0.f;
#pragma unroll
            for (int j = 0; j < 4; j++) {
                float p = __expf(s[j][r] - mnew);
                rs += p;
                *(short*)(PsB + q * 128 + 16 * ((2 * j + (c >> 3)) ^ (q & 7)) + 2 * (c & 7)) = f2bfs(p);
            }
#pragma unroll
            for (int mk = 1; mk < 16; mk <<= 1) rs += __shfl_xor(rs, mk, 64);
            l_r[r] = l_r[r] * sc + rs;
            m_r[r] = mnew;
#pragma unroll
            for (int jd = 0; jd < 4; jd++) oacc[jd][r] *= sc;
        }
        __syncthreads();   // Ps visible (cross-lane), K/V reads done before overwrite next iter

        // ---- O += P V : A = P frag (q=c rows), B = Vt frag
#pragma unroll
        for (int ks = 0; ks < 2; ks++) {
            short8v pa = *(const short8v*)(PsB + c * 128 + 16 * ((ks * 4 + g4) ^ (c & 7)));
#pragma unroll
            for (int jd = 0; jd < 4; jd++) {
                int row = jd * 16 + c;
                short8v vb = *(const short8v*)(VlB + row * 128 + 16 * ((ks * 4 + g4) ^ (row & 7)));
                oacc[jd] = mfma16(pa, vb, oacc[jd]);
            }
        }
    }

    // ---- epilogue: divide by l, write hi/lo bf16 at (t*B+b, h*64+d)
    int b = bh >> 4, h = bh & 15;
#pragma unroll
    for (int r = 0; r < 4; r++) {
        float inv = 1.0f / l_r[r];
        int t = qt * 64 + w * 16 + g4 * 4 + r;
        size_t rb = (size_t)(t * B_SZ + b) * C_DIM + h * 64;
#pragma unroll
        for (int jd = 0; jd < 4; jd++) {
            float v = oacc[jd][r] * inv;
            short hs, ls;
            split2(v, hs, ls);
            *(short*)&Ohi[rb + jd * 16 + c] = hs;
            *(short*)&Olo[rb + jd * 16 + c] = ls;
        }
    }
}

// ---------------------------------------------------------------- launcher
extern "C" void kernel_launch(void* const* d_in, const int* in_sizes, int n_in,
                              void* d_out, int out_size, void* d_ws, size_t ws_size,
                              hipStream_t stream) {
    (void)in_sizes; (void)n_in; (void)out_size; (void)ws_size;
    const float* x     = (const float*)d_in[0];
    const float* in_w  = (const float*)d_in[1];
    const float* in_b  = (const float*)d_in[2];
    const float* out_w = (const float*)d_in[3];
    const float* out_b = (const float*)d_in[4];
    const float* ln1_g = (const float*)d_in[5];
    const float* ln1_b = (const float*)d_in[6];
    const float* ln2_g = (const float*)d_in[7];
    const float* ln2_b = (const float*)d_in[8];
    const float* w1    = (const float*)d_in[9];
    const float* b1    = (const float*)d_in[10];
    const float* w2    = (const float*)d_in[11];
    const float* b2    = (const float*)d_in[12];
    float* out = (float*)d_out;
    char* ws = (char*)d_ws;

    const size_t MB = 1 << 20;
    // persistent weight splits [0,48MB)
    bf16* inw_h  = (bf16*)(ws + 0 * MB);
    bf16* inw_l  = (bf16*)(ws + 6 * MB);
    bf16* outw_h = (bf16*)(ws + 12 * MB);
    bf16* outw_l = (bf16*)(ws + 14 * MB);
    bf16* w1_h   = (bf16*)(ws + 16 * MB);
    bf16* w1_l   = (bf16*)(ws + 24 * MB);
    bf16* w2_h   = (bf16*)(ws + 32 * MB);
    bf16* w2_l   = (bf16*)(ws + 40 * MB);
    // activations (with lifetime reuse)
    bf16* ln1o_h = (bf16*)(ws + 48 * MB);   // dead after QKV gemm
    bf16* ln1o_l = (bf16*)(ws + 56 * MB);
    bf16* qkv    = (bf16*)(ws + 64 * MB);   // 24MB, dead after rope/vt
    bf16* Qg     = (bf16*)(ws + 88 * MB);   // dead after attn
    bf16* Kg     = (bf16*)(ws + 96 * MB);
    bf16* Vt     = (bf16*)(ws + 104 * MB);
    bf16* O_h    = (bf16*)(ws + 48 * MB);   // reuse ln1o slot
    bf16* O_l    = (bf16*)(ws + 56 * MB);
    float* x2    = (float*)(ws + 112 * MB); // 16MB, live to end
    bf16* h2_h   = (bf16*)(ws + 64 * MB);   // reuse qkv slot
    bf16* h2_l   = (bf16*)(ws + 72 * MB);
    bf16* f1     = (bf16*)(ws + 80 * MB);   // 32MB, overlays dead Q/K/Vt

    // 0. weight hi/lo splits
    split_kernel<<<3072, 256, 0, stream>>>(in_w, inw_h, inw_l);
    split_kernel<<<1024, 256, 0, stream>>>(out_w, outw_h, outw_l);
    split_kernel<<<4096, 256, 0, stream>>>(w1, w1_h, w1_l);
    split_kernel<<<4096, 256, 0, stream>>>(w2, w2_h, w2_l);
    // 1. LN1 -> split
    ln_split_kernel<<<NT, 256, 0, stream>>>(x, ln1_g, ln1_b, ln1o_h, ln1o_l);
    // 2. QKV projection (split A,B; bf16 out)
    gemm_bf16<0, true, true><<<dim3(C3 / 128, NT / 128), 256, 0, stream>>>(
        ln1o_h, ln1o_l, inw_h, inw_l, in_b, nullptr, nullptr, qkv, C3, C_DIM);
    // 3. RoPE q,k + 4. V transpose
    rope_kernel<<<(BH * T_LEN * 32) / 256, 256, 0, stream>>>(qkv, Qg, Kg);
    vt_kernel<<<dim3(T_LEN / 64, BH), 256, 0, stream>>>(qkv, Vt);
    // 5. causal flash attention (bf16 MFMA), O as hi/lo split
    attn_kernel<<<dim3(T_LEN / 64, BH), 256, 0, stream>>>(Qg, Kg, Vt, O_h, O_l);
    // 6. output projection + residual(x) -> x2 fp32
    gemm_bf16<2, true, false><<<dim3(C_DIM / 128, NT / 128), 256, 0, stream>>>(
        O_h, O_l, outw_h, outw_l, out_b, x, x2, nullptr, C_DIM, C_DIM);
    // 7. LN2 -> split
    ln_split_kernel<<<NT, 256, 0, stream>>>(x2, ln2_g, ln2_b, h2_h, h2_l);
    // 8. FFN up + GELU -> f1 bf16
    gemm_bf16<1, true, true><<<dim3(F_DIM / 128, NT / 128), 256, 0, stream>>>(
        h2_h, h2_l, w1_h, w1_l, b1, nullptr, nullptr, f1, F_DIM, C_DIM);
    // 9. FFN down + residual(x2) -> out fp32 (A direct bf16, B split)
    gemm_bf16<2, false, false><<<dim3(C_DIM / 128, NT / 128), 256, 0, stream>>>(
        f1, nullptr, w2_h, w2_l, b2, x2, out, nullptr, C_DIM, F_DIM);
}

// Round 10
// 624.522 us; speedup vs baseline: 1.0252x; 1.0252x over previous
//
#include <hip/hip_runtime.h>
#include <hip/hip_bf16.h>
#include <math.h>

#define T_LEN 2048
#define B_SZ  2
#define C_DIM 1024
#define H_NUM 16
#define D_HEAD 64
#define F_DIM 4096
#define NT    (T_LEN * B_SZ)   // 4096 tokens
#define BH    (B_SZ * H_NUM)   // 32 head-batches
#define C3    (3 * C_DIM)      // 3072

typedef __attribute__((ext_vector_type(8))) short short8v;  // 8 bf16 = 1 MFMA operand frag
typedef __attribute__((ext_vector_type(4))) float f32x4;    // 16x16 MFMA C/D frag
typedef __hip_bfloat16 bf16;

__device__ __forceinline__ float bf2f(bf16 v) { return __bfloat162float(v); }
__device__ __forceinline__ bf16  f2bf(float f) { return __float2bfloat16(f); }
__device__ __forceinline__ short f2bfs(float f) { bf16 h = __float2bfloat16(f); return *(short*)&h; }
__device__ __forceinline__ void split2(float v, short& h, short& l) {
    bf16 hb = __float2bfloat16(v);
    bf16 lb = __float2bfloat16(v - __bfloat162float(hb));
    h = *(short*)&hb; l = *(short*)&lb;
}
__device__ __forceinline__ f32x4 mfma16(short8v a, short8v b, f32x4 c) {
    return __builtin_amdgcn_mfma_f32_16x16x32_bf16(a, b, c, 0, 0, 0);
}
// async global->LDS, 16B per lane; LDS dest = wave-uniform base + lane*16
__device__ __forceinline__ void async16(const void* g, void* lds) {
    __builtin_amdgcn_global_load_lds(
        (const __attribute__((address_space(1))) void*)g,
        (__attribute__((address_space(3))) void*)lds, 16, 0, 0);
}

// ---------------------------------------------------------------- block sum
__device__ __forceinline__ float block_sum_256(float val, float* sred) {
#pragma unroll
    for (int off = 32; off > 0; off >>= 1)
        val += __shfl_down(val, off, 64);
    int lane = threadIdx.x & 63;
    int wid  = threadIdx.x >> 6;
    if (lane == 0) sred[wid] = val;
    __syncthreads();
    float r = sred[0] + sred[1] + sred[2] + sred[3];
    __syncthreads();
    return r;
}

// ---------------------------------------------------------------- fp32 -> bf16 hi/lo split (weights)
__global__ __launch_bounds__(256) void split_kernel(const float* __restrict__ src,
                                                    bf16* __restrict__ hi, bf16* __restrict__ lo) {
    int i = blockIdx.x * 256 + threadIdx.x;   // one float4 per thread; n % 1024 == 0
    float4 v = ((const float4*)src)[i];
    short4 hv, lv;
    split2(v.x, hv.x, lv.x); split2(v.y, hv.y, lv.y);
    split2(v.z, hv.z, lv.z); split2(v.w, hv.w, lv.w);
    ((short4*)hi)[i] = hv;
    ((short4*)lo)[i] = lv;
}

// ---------------------------------------------------------------- LayerNorm -> bf16 hi/lo
__global__ __launch_bounds__(256) void ln_split_kernel(const float* __restrict__ x,
                                                       const float* __restrict__ g,
                                                       const float* __restrict__ b,
                                                       bf16* __restrict__ oh, bf16* __restrict__ ol) {
    __shared__ float sred[4];
    int row = blockIdx.x;
    int tid = threadIdx.x;
    const float* xr = x + (size_t)row * C_DIM;
    float4 xv = *(const float4*)(xr + tid * 4);
    float s = xv.x + xv.y + xv.z + xv.w;
    s = block_sum_256(s, sred);
    float mu = s * (1.0f / C_DIM);
    float d0 = xv.x - mu, d1 = xv.y - mu, d2 = xv.z - mu, d3 = xv.w - mu;
    float vs = d0 * d0 + d1 * d1 + d2 * d2 + d3 * d3;
    vs = block_sum_256(vs, sred);
    float rstd = rsqrtf(vs * (1.0f / C_DIM) + 1e-5f);
    float4 gv = *(const float4*)(g + tid * 4);
    float4 bv = *(const float4*)(b + tid * 4);
    float y0 = d0 * rstd * gv.x + bv.x, y1 = d1 * rstd * gv.y + bv.y;
    float y2 = d2 * rstd * gv.z + bv.z, y3 = d3 * rstd * gv.w + bv.w;
    short4 hv, lv;
    split2(y0, hv.x, lv.x); split2(y1, hv.y, lv.y);
    split2(y2, hv.z, lv.z); split2(y3, hv.w, lv.w);
    size_t base = (size_t)row * C_DIM / 4 + tid;
    ((short4*)oh)[base] = hv;
    ((short4*)ol)[base] = lv;
}

// ---------------------------------------------------------------- split-bf16 MFMA GEMM (NT)
// C[m,n] = sum_k A[m,k]*Bw[n,k] + bias[n] (+gelu | +res). acc = Ah*Bh + Ah*Bl (+ Al*Bh if ASPLIT).
// 128x128 tile, BK=32, 4 waves (2x2), per-wave 64x64 = 4x4 frags of 16x16x32.
// DOUBLE-BUFFERED global_load_lds staging (T3 minimal 2-phase): prologue stages tile 0;
// each iter issues STAGE(kt+1 -> page^1) FIRST (loads in flight under MFMA), computes
// page, then ONE __syncthreads() (drains prefetch vmcnt + protects buffer reuse).
// LDS logical layout: position (row, chunk c) holds global 16B-chunk c ^ ((row>>1)&3);
// linear LDS dest + inverse-swizzled per-lane GLOBAL source; frag read applies the same
// XOR -> <=2-way banks. Round-8 post-mortem: serial stage->drain->compute was
// latency-bound (MfmaUtil 18%, 147us FFN-down); this restores the overlap.
template <int EPI, bool ASPLIT, bool OUTBF16>
__global__ __launch_bounds__(256) void gemm_bf16(const bf16* __restrict__ Ah, const bf16* __restrict__ Al,
                                                 const bf16* __restrict__ Bh, const bf16* __restrict__ Bl,
                                                 const float* __restrict__ bias, const float* __restrict__ res,
                                                 float* __restrict__ Cf, bf16* __restrict__ Cb,
                                                 int N, int K) {
    constexpr int NBUF = ASPLIT ? 4 : 3;       // {Ah, Bh, Bl[, Al]} x 8KB each
    __shared__ __align__(16) char LDS[2][NBUF * 8192];

    int tid = threadIdx.x;
    int w = tid >> 6, l = tid & 63;
    int c = l & 15, g4 = l >> 4;
    int wm = w >> 1, wn = w & 1;
    int bn = blockIdx.x, bm = blockIdx.y;

    f32x4 acc[4][4];
#pragma unroll
    for (int i = 0; i < 4; i++)
#pragma unroll
        for (int j = 0; j < 4; j++) acc[i][j] = (f32x4){0.f, 0.f, 0.f, 0.f};

    const bf16* gB[4];
    gB[0] = Ah + (size_t)bm * 128 * K;
    gB[1] = Bh + (size_t)bn * 128 * K;
    gB[2] = Bl + (size_t)bn * 128 * K;
    gB[3] = ASPLIT ? (Al + (size_t)bm * 128 * K) : gB[0];
    const int NSEG = NBUF * 8;                 // 1KB segments (16 rows) per buffer
    int lr4 = l >> 2, lc4 = l & 3;             // lane -> (row-in-seg, chunk)

    auto STAGE = [&](int kt, int pg) {
#pragma unroll
        for (int sidx = w; sidx < NSEG; sidx += 4) {
            int bsel = sidx >> 3, seg = sidx & 7;
            int r = seg * 16 + lr4;
            int cs = lc4 ^ ((r >> 1) & 3);                     // inverse-swizzled source chunk
            const bf16* g = gB[bsel] + (size_t)r * K + kt + cs * 8;
            async16(g, LDS[pg] + bsel * 8192 + seg * 1024);    // + lane*16 implicit
        }
    };

    STAGE(0, 0);
    __syncthreads();              // tile 0 staged (vmcnt drained by barrier)
    int cur = 0;
    for (int kt = 0; kt < K; kt += 32) {
        if (kt + 32 < K) STAGE(kt + 32, cur ^ 1);   // prefetch in flight under compute

        char* base = LDS[cur];
        char* LAhB = base;
        char* LBhB = base + 8192;
        char* LBlB = base + 16384;
        char* LAlB = base + 24576;                  // deref'd only if ASPLIT

        short8v fah[4], fal[4], fbh[4], fbl[4];
#pragma unroll
        for (int i = 0; i < 4; i++) {
            int row = wm * 64 + i * 16 + c;
            int off = row * 64 + 16 * (g4 ^ ((row >> 1) & 3));
            fah[i] = *(const short8v*)(LAhB + off);
            if (ASPLIT) fal[i] = *(const short8v*)(LAlB + off);
        }
#pragma unroll
        for (int j = 0; j < 4; j++) {
            int row = wn * 64 + j * 16 + c;
            int off = row * 64 + 16 * (g4 ^ ((row >> 1) & 3));
            fbh[j] = *(const short8v*)(LBhB + off);
            fbl[j] = *(const short8v*)(LBlB + off);
        }
#pragma unroll
        for (int i = 0; i < 4; i++)
#pragma unroll
            for (int j = 0; j < 4; j++) {
                f32x4 t = acc[i][j];
                t = mfma16(fah[i], fbl[j], t);
                if (ASPLIT) t = mfma16(fal[i], fbh[j], t);
                t = mfma16(fah[i], fbh[j], t);
                acc[i][j] = t;
            }
        __syncthreads();          // prefetch landed; all reads of LDS[cur] done
        cur ^= 1;
    }

#pragma unroll
    for (int i = 0; i < 4; i++)
#pragma unroll
        for (int j = 0; j < 4; j++) {
            int colg = bn * 128 + wn * 64 + j * 16 + c;
            float bv = bias[colg];
#pragma unroll
            for (int r = 0; r < 4; r++) {
                int rowg = bm * 128 + wm * 64 + i * 16 + g4 * 4 + r;
                float v = acc[i][j][r] + bv;
                if (EPI == 1) {
                    float t = tanhf(0.7978845608028654f * (v + 0.044715f * v * v * v));
                    v = 0.5f * v * (1.0f + t);
                } else if (EPI == 2) {
                    v += res[(size_t)rowg * N + colg];
                }
                if (OUTBF16) Cb[(size_t)rowg * N + colg] = f2bf(v);
                else         Cf[(size_t)rowg * N + colg] = v;
            }
        }
}

// ---------------------------------------------------------------- RoPE (q,k) from bf16 qkv
__global__ __launch_bounds__(256) void rope_kernel(const bf16* __restrict__ qkv,
                                                   bf16* __restrict__ Q, bf16* __restrict__ K) {
    int idx = blockIdx.x * 256 + threadIdx.x;  // BH * T * 32
    int d  = idx & 31;
    int t  = (idx >> 5) & (T_LEN - 1);
    int bh = idx >> 16;
    int b  = bh >> 4;
    int h  = bh & 15;
    size_t row = (size_t)(t * B_SZ + b) * C3 + h * D_HEAD + d;
    float q0 = bf2f(qkv[row]),          q1 = bf2f(qkv[row + 32]);
    float k0 = bf2f(qkv[row + C_DIM]),  k1 = bf2f(qkv[row + C_DIM + 32]);
    q0 *= 0.125f; q1 *= 0.125f;               // D^-0.5
    float theta = exp2f((float)d * (-13.287712379549449f / 32.0f));  // 10000^(-d/32)
    float ang = (float)t * theta;
    float sn, cs;
    sincosf(ang, &sn, &cs);
    size_t ob = ((size_t)bh * T_LEN + t) * D_HEAD + d;
    Q[ob]      = f2bf(cs * q0 - sn * q1);
    Q[ob + 32] = f2bf(cs * q1 + sn * q0);
    K[ob]      = f2bf(cs * k0 - sn * k1);
    K[ob + 32] = f2bf(cs * k1 + sn * k0);
}

// ---------------------------------------------------------------- V transpose: qkv v-part -> Vt (BH, D, T)
// LDS elem(t,d) @ byte t*128 + 16*((d>>3)^((t>>3)&7)) + 2*(d&7): both phases <=2-way banks.
__global__ __launch_bounds__(256) void vt_kernel(const bf16* __restrict__ qkv, bf16* __restrict__ Vt) {
    __shared__ __align__(16) short L[64 * 64];
    char* LB = (char*)L;
    int qt = blockIdx.x, bh = blockIdx.y;
    int b = bh >> 4, h = bh & 15;
    int tid = threadIdx.x;
    int t0 = qt * 64;
#pragma unroll
    for (int e = 0; e < 2; e++) {
        int t = (tid >> 3) + e * 32, dc = tid & 7;
        short8v v = *(const short8v*)(qkv + (size_t)((t0 + t) * B_SZ + b) * C3 + 2 * C_DIM + h * 64 + dc * 8);
        *(short8v*)(LB + t * 128 + 16 * (dc ^ ((t >> 3) & 7))) = v;
    }
    __syncthreads();
    int d = tid & 63, tcb = tid >> 6;   // 16 t per thread
    short8v v0, v1;
#pragma unroll
    for (int i = 0; i < 8; i++) {
        int t = tcb * 16 + i;
        v0[i] = *(const short*)(LB + t * 128 + 16 * ((d >> 3) ^ ((t >> 3) & 7)) + 2 * (d & 7));
    }
#pragma unroll
    for (int i = 0; i < 8; i++) {
        int t = tcb * 16 + 8 + i;
        v1[i] = *(const short*)(LB + t * 128 + 16 * ((d >> 3) ^ ((t >> 3) & 7)) + 2 * (d & 7));
    }
    bf16* op = Vt + ((size_t)bh * 64 + d) * T_LEN + t0 + tcb * 16;
    *(short8v*)(op)     = v0;
    *(short8v*)(op + 8) = v1;
}

// ---------------------------------------------------------------- causal flash attention, bf16 MFMA
// grid (T/64, BH), 4 waves. Wave w: 16 q-rows. KV tile 64. Q in regs; K/Vt staged in swizzled LDS.
// LPT balance: qt = gridDim.x-1-blockIdx.x (heaviest q-tiles dispatch first).
// K elem(kv,d): byte kv*128 + 16*((d>>3)^(kv&7)) + 2*(d&7)
// Vt elem(d,kv): byte d*128 + 16*((kv>>3)^(d&7)) + 2*(kv&7)
// Ps elem(q,kv) per wave: byte q*128 + 16*((kv>>3)^(q&7)) + 2*(kv&7)
__global__ __launch_bounds__(256) void attn_kernel(const bf16* __restrict__ Qg, const bf16* __restrict__ Kg,
                                                   const bf16* __restrict__ Vt,
                                                   bf16* __restrict__ Ohi, bf16* __restrict__ Olo) {
    __shared__ __align__(16) short Kl[64 * 64];
    __shared__ __align__(16) short Vl[64 * 64];
    __shared__ __align__(16) short Ps[4 * 16 * 64];
    char* KlB = (char*)Kl; char* VlB = (char*)Vl;
    int qt = gridDim.x - 1 - blockIdx.x;     // LPT: heaviest q-tiles first
    int bh = blockIdx.y;
    int tid = threadIdx.x;
    int w = tid >> 6, l = tid & 63;
    int c = l & 15, g4 = l >> 4;
    char* PsB = (char*)Ps + w * 2048;

    // Q fragments (2 k-steps of 32 over D=64), direct from global
    int q0 = qt * 64 + w * 16;
    const bf16* Qb = Qg + ((size_t)bh * T_LEN + q0 + c) * 64 + g4 * 8;
    short8v qf0 = *(const short8v*)(Qb);
    short8v qf1 = *(const short8v*)(Qb + 32);

    f32x4 oacc[4];
    float m_r[4], l_r[4];
#pragma unroll
    for (int i = 0; i < 4; i++) { oacc[i] = (f32x4){0.f,0.f,0.f,0.f}; m_r[i] = -1e30f; l_r[i] = 0.f; }

    int skv = tid >> 3, sc8 = tid & 7;      // staging coords
    for (int kt = 0; kt <= qt; kt++) {
        int kv0 = kt * 64;
        // ---- stage K tile + Vt tile (reg -> swizzled LDS)
        short8v kreg[2], vreg[2];
#pragma unroll
        for (int e = 0; e < 2; e++) {
            int rkv = skv + e * 32;
            kreg[e] = *(const short8v*)(Kg + ((size_t)bh * T_LEN + kv0 + rkv) * 64 + sc8 * 8);
            vreg[e] = *(const short8v*)(Vt + ((size_t)bh * 64 + rkv) * T_LEN + kv0 + sc8 * 8);
        }
        __syncthreads();   // prev tile's LDS reads done
#pragma unroll
        for (int e = 0; e < 2; e++) {
            int rkv = skv + e * 32;
            *(short8v*)(KlB + rkv * 128 + 16 * (sc8 ^ (rkv & 7))) = kreg[e];
            *(short8v*)(VlB + rkv * 128 + 16 * (sc8 ^ (rkv & 7))) = vreg[e];
        }
        __syncthreads();

        // ---- scores S = Q K^T : 4 kv-frags x 2 d-steps
        f32x4 s[4];
#pragma unroll
        for (int j = 0; j < 4; j++) s[j] = (f32x4){0.f,0.f,0.f,0.f};
#pragma unroll
        for (int j = 0; j < 4; j++) {
            int row = j * 16 + c;
            short8v kb0 = *(const short8v*)(KlB + row * 128 + 16 * ((g4)     ^ (row & 7)));
            short8v kb1 = *(const short8v*)(KlB + row * 128 + 16 * ((4 + g4) ^ (row & 7)));
            s[j] = mfma16(qf0, kb0, s[j]);
            s[j] = mfma16(qf1, kb1, s[j]);
        }
        if (kt == qt) {   // causal mask within diagonal tile
#pragma unroll
            for (int j = 0; j < 4; j++)
#pragma unroll
                for (int r = 0; r < 4; r++)
                    if (j * 16 + c > w * 16 + g4 * 4 + r) s[j][r] = -1e30f;
        }

        // ---- online softmax (rows r; 16 cols per frag across lanes c)
#pragma unroll
        for (int r = 0; r < 4; r++) {
            float tm = fmaxf(fmaxf(s[0][r], s[1][r]), fmaxf(s[2][r], s[3][r]));
#pragma unroll
            for (int mk = 1; mk < 16; mk <<= 1) tm = fmaxf(tm, __shfl_xor(tm, mk, 64));
            float mnew = fmaxf(m_r[r], tm);
            float sc = __expf(m_r[r] - mnew);
            int q = g4 * 4 + r;
            float rs = 0.f;
#pragma unroll
            for (int j = 0; j < 4; j++) {
                float p = __expf(s[j][r] - mnew);
                rs += p;
                *(short*)(PsB + q * 128 + 16 * ((2 * j + (c >> 3)) ^ (q & 7)) + 2 * (c & 7)) = f2bfs(p);
            }
#pragma unroll
            for (int mk = 1; mk < 16; mk <<= 1) rs += __shfl_xor(rs, mk, 64);
            l_r[r] = l_r[r] * sc + rs;
            m_r[r] = mnew;
#pragma unroll
            for (int jd = 0; jd < 4; jd++) oacc[jd][r] *= sc;
        }
        __syncthreads();   // Ps visible (cross-lane), K/V reads done before overwrite next iter

        // ---- O += P V : A = P frag (q=c rows), B = Vt frag
#pragma unroll
        for (int ks = 0; ks < 2; ks++) {
            short8v pa = *(const short8v*)(PsB + c * 128 + 16 * ((ks * 4 + g4) ^ (c & 7)));
#pragma unroll
            for (int jd = 0; jd < 4; jd++) {
                int row = jd * 16 + c;
                short8v vb = *(const short8v*)(VlB + row * 128 + 16 * ((ks * 4 + g4) ^ (row & 7)));
                oacc[jd] = mfma16(pa, vb, oacc[jd]);
            }
        }
    }

    // ---- epilogue: divide by l, write hi/lo bf16 at (t*B+b, h*64+d)
    int b = bh >> 4, h = bh & 15;
#pragma unroll
    for (int r = 0; r < 4; r++) {
        float inv = 1.0f / l_r[r];
        int t = qt * 64 + w * 16 + g4 * 4 + r;
        size_t rb = (size_t)(t * B_SZ + b) * C_DIM + h * 64;
#pragma unroll
        for (int jd = 0; jd < 4; jd++) {
            float v = oacc[jd][r] * inv;
            short hs, ls;
            split2(v, hs, ls);
            *(short*)&Ohi[rb + jd * 16 + c] = hs;
            *(short*)&Olo[rb + jd * 16 + c] = ls;
        }
    }
}

// ---------------------------------------------------------------- launcher
extern "C" void kernel_launch(void* const* d_in, const int* in_sizes, int n_in,
                              void* d_out, int out_size, void* d_ws, size_t ws_size,
                              hipStream_t stream) {
    (void)in_sizes; (void)n_in; (void)out_size; (void)ws_size;
    const float* x     = (const float*)d_in[0];
    const float* in_w  = (const float*)d_in[1];
    const float* in_b  = (const float*)d_in[2];
    const float* out_w = (const float*)d_in[3];
    const float* out_b = (const float*)d_in[4];
    const float* ln1_g = (const float*)d_in[5];
    const float* ln1_b = (const float*)d_in[6];
    const float* ln2_g = (const float*)d_in[7];
    const float* ln2_b = (const float*)d_in[8];
    const float* w1    = (const float*)d_in[9];
    const float* b1    = (const float*)d_in[10];
    const float* w2    = (const float*)d_in[11];
    const float* b2    = (const float*)d_in[12];
    float* out = (float*)d_out;
    char* ws = (char*)d_ws;

    const size_t MB = 1 << 20;
    // persistent weight splits [0,48MB)
    bf16* inw_h  = (bf16*)(ws + 0 * MB);
    bf16* inw_l  = (bf16*)(ws + 6 * MB);
    bf16* outw_h = (bf16*)(ws + 12 * MB);
    bf16* outw_l = (bf16*)(ws + 14 * MB);
    bf16* w1_h   = (bf16*)(ws + 16 * MB);
    bf16* w1_l   = (bf16*)(ws + 24 * MB);
    bf16* w2_h   = (bf16*)(ws + 32 * MB);
    bf16* w2_l   = (bf16*)(ws + 40 * MB);
    // activations (with lifetime reuse)
    bf16* ln1o_h = (bf16*)(ws + 48 * MB);   // dead after QKV gemm
    bf16* ln1o_l = (bf16*)(ws + 56 * MB);
    bf16* qkv    = (bf16*)(ws + 64 * MB);   // 24MB, dead after rope/vt
    bf16* Qg     = (bf16*)(ws + 88 * MB);   // dead after attn
    bf16* Kg     = (bf16*)(ws + 96 * MB);
    bf16* Vt     = (bf16*)(ws + 104 * MB);
    bf16* O_h    = (bf16*)(ws + 48 * MB);   // reuse ln1o slot
    bf16* O_l    = (bf16*)(ws + 56 * MB);
    float* x2    = (float*)(ws + 112 * MB); // 16MB, live to end
    bf16* h2_h   = (bf16*)(ws + 64 * MB);   // reuse qkv slot
    bf16* h2_l   = (bf16*)(ws + 72 * MB);
    bf16* f1     = (bf16*)(ws + 80 * MB);   // 32MB, overlays dead Q/K/Vt

    // 0. weight hi/lo splits
    split_kernel<<<3072, 256, 0, stream>>>(in_w, inw_h, inw_l);
    split_kernel<<<1024, 256, 0, stream>>>(out_w, outw_h, outw_l);
    split_kernel<<<4096, 256, 0, stream>>>(w1, w1_h, w1_l);
    split_kernel<<<4096, 256, 0, stream>>>(w2, w2_h, w2_l);
    // 1. LN1 -> split
    ln_split_kernel<<<NT, 256, 0, stream>>>(x, ln1_g, ln1_b, ln1o_h, ln1o_l);
    // 2. QKV projection (split A,B; bf16 out)
    gemm_bf16<0, true, true><<<dim3(C3 / 128, NT / 128), 256, 0, stream>>>(
        ln1o_h, ln1o_l, inw_h, inw_l, in_b, nullptr, nullptr, qkv, C3, C_DIM);
    // 3. RoPE q,k + 4. V transpose
    rope_kernel<<<(BH * T_LEN * 32) / 256, 256, 0, stream>>>(qkv, Qg, Kg);
    vt_kernel<<<dim3(T_LEN / 64, BH), 256, 0, stream>>>(qkv, Vt);
    // 5. causal flash attention (bf16 MFMA), O as hi/lo split
    attn_kernel<<<dim3(T_LEN / 64, BH), 256, 0, stream>>>(Qg, Kg, Vt, O_h, O_l);
    // 6. output projection + residual(x) -> x2 fp32
    gemm_bf16<2, true, false><<<dim3(C_DIM / 128, NT / 128), 256, 0, stream>>>(
        O_h, O_l, outw_h, outw_l, out_b, x, x2, nullptr, C_DIM, C_DIM);
    // 7. LN2 -> split
    ln_split_kernel<<<NT, 256, 0, stream>>>(x2, ln2_g, ln2_b, h2_h, h2_l);
    // 8. FFN up + GELU -> f1 bf16
    gemm_bf16<1, true, true><<<dim3(F_DIM / 128, NT / 128), 256, 0, stream>>>(
        h2_h, h2_l, w1_h, w1_l, b1, nullptr, nullptr, f1, F_DIM, C_DIM);
    // 9. FFN down + residual(x2) -> out fp32 (A direct bf16, B split)
    gemm_bf16<2, false, false><<<dim3(C_DIM / 128, NT / 128), 256, 0, stream>>>(
        f1, nullptr, w2_h, w2_l, b2, x2, out, nullptr, C_DIM, F_DIM);
}

// Round 11
// 548.233 us; speedup vs baseline: 1.1678x; 1.1392x over previous
//
#include <hip/hip_runtime.h>
#include <hip/hip_bf16.h>
#include <math.h>

#define T_LEN 2048
#define B_SZ  2
#define C_DIM 1024
#define H_NUM 16
#define D_HEAD 64
#define F_DIM 4096
#define NT    (T_LEN * B_SZ)   // 4096 tokens
#define BH    (B_SZ * H_NUM)   // 32 head-batches
#define C3    (3 * C_DIM)      // 3072
#define NQT   (T_LEN / 64)     // 32 q-tiles

typedef __attribute__((ext_vector_type(8))) short short8v;  // 8 bf16 = 1 MFMA operand frag
typedef __attribute__((ext_vector_type(4))) float f32x4;    // 16x16 MFMA C/D frag
typedef __hip_bfloat16 bf16;

__device__ __forceinline__ float bf2f(bf16 v) { return __bfloat162float(v); }
__device__ __forceinline__ bf16  f2bf(float f) { return __float2bfloat16(f); }
__device__ __forceinline__ short f2bfs(float f) { bf16 h = __float2bfloat16(f); return *(short*)&h; }
__device__ __forceinline__ void split2(float v, short& h, short& l) {
    bf16 hb = __float2bfloat16(v);
    bf16 lb = __float2bfloat16(v - __bfloat162float(hb));
    h = *(short*)&hb; l = *(short*)&lb;
}
__device__ __forceinline__ f32x4 mfma16(short8v a, short8v b, f32x4 c) {
    return __builtin_amdgcn_mfma_f32_16x16x32_bf16(a, b, c, 0, 0, 0);
}
// async global->LDS, 16B per lane; LDS dest = wave-uniform base + lane*16
__device__ __forceinline__ void async16(const void* g, void* lds) {
    __builtin_amdgcn_global_load_lds(
        (const __attribute__((address_space(1))) void*)g,
        (__attribute__((address_space(3))) void*)lds, 16, 0, 0);
}

// ---------------------------------------------------------------- block sum
__device__ __forceinline__ float block_sum_256(float val, float* sred) {
#pragma unroll
    for (int off = 32; off > 0; off >>= 1)
        val += __shfl_down(val, off, 64);
    int lane = threadIdx.x & 63;
    int wid  = threadIdx.x >> 6;
    if (lane == 0) sred[wid] = val;
    __syncthreads();
    float r = sred[0] + sred[1] + sred[2] + sred[3];
    __syncthreads();
    return r;
}

// ---------------------------------------------------------------- fp32 -> bf16 hi/lo split (weights)
__global__ __launch_bounds__(256) void split_kernel(const float* __restrict__ src,
                                                    bf16* __restrict__ hi, bf16* __restrict__ lo) {
    int i = blockIdx.x * 256 + threadIdx.x;   // one float4 per thread; n % 1024 == 0
    float4 v = ((const float4*)src)[i];
    short4 hv, lv;
    split2(v.x, hv.x, lv.x); split2(v.y, hv.y, lv.y);
    split2(v.z, hv.z, lv.z); split2(v.w, hv.w, lv.w);
    ((short4*)hi)[i] = hv;
    ((short4*)lo)[i] = lv;
}

// ---------------------------------------------------------------- LayerNorm -> bf16 hi/lo
__global__ __launch_bounds__(256) void ln_split_kernel(const float* __restrict__ x,
                                                       const float* __restrict__ g,
                                                       const float* __restrict__ b,
                                                       bf16* __restrict__ oh, bf16* __restrict__ ol) {
    __shared__ float sred[4];
    int row = blockIdx.x;
    int tid = threadIdx.x;
    const float* xr = x + (size_t)row * C_DIM;
    float4 xv = *(const float4*)(xr + tid * 4);
    float s = xv.x + xv.y + xv.z + xv.w;
    s = block_sum_256(s, sred);
    float mu = s * (1.0f / C_DIM);
    float d0 = xv.x - mu, d1 = xv.y - mu, d2 = xv.z - mu, d3 = xv.w - mu;
    float vs = d0 * d0 + d1 * d1 + d2 * d2 + d3 * d3;
    vs = block_sum_256(vs, sred);
    float rstd = rsqrtf(vs * (1.0f / C_DIM) + 1e-5f);
    float4 gv = *(const float4*)(g + tid * 4);
    float4 bv = *(const float4*)(b + tid * 4);
    float y0 = d0 * rstd * gv.x + bv.x, y1 = d1 * rstd * gv.y + bv.y;
    float y2 = d2 * rstd * gv.z + bv.z, y3 = d3 * rstd * gv.w + bv.w;
    short4 hv, lv;
    split2(y0, hv.x, lv.x); split2(y1, hv.y, lv.y);
    split2(y2, hv.z, lv.z); split2(y3, hv.w, lv.w);
    size_t base = (size_t)row * C_DIM / 4 + tid;
    ((short4*)oh)[base] = hv;
    ((short4*)ol)[base] = lv;
}

// ---------------------------------------------------------------- split-bf16 MFMA GEMM (NT)
// C[m,n] = sum_k A[m,k]*Bw[n,k] + bias[n] (+gelu | +res). acc = Ah*Bh + Ah*Bl (+ Al*Bh if ASPLIT).
// 128x128 tile, BK=32, 4 waves (2x2), per-wave 64x64 = 4x4 frags of 16x16x32.
// DOUBLE-BUFFERED global_load_lds staging (T3 minimal 2-phase): prologue stages tile 0;
// each iter issues STAGE(kt+1 -> page^1) FIRST (loads in flight under MFMA), computes
// page, then ONE __syncthreads() (drains prefetch vmcnt + protects buffer reuse).
// LDS logical layout: position (row, chunk c) holds global 16B-chunk c ^ ((row>>1)&3);
// linear LDS dest + inverse-swizzled per-lane GLOBAL source; frag read applies the same
// XOR -> <=2-way banks.
template <int EPI, bool ASPLIT, bool OUTBF16>
__global__ __launch_bounds__(256) void gemm_bf16(const bf16* __restrict__ Ah, const bf16* __restrict__ Al,
                                                 const bf16* __restrict__ Bh, const bf16* __restrict__ Bl,
                                                 const float* __restrict__ bias, const float* __restrict__ res,
                                                 float* __restrict__ Cf, bf16* __restrict__ Cb,
                                                 int N, int K) {
    constexpr int NBUF = ASPLIT ? 4 : 3;       // {Ah, Bh, Bl[, Al]} x 8KB each
    __shared__ __align__(16) char LDS[2][NBUF * 8192];

    int tid = threadIdx.x;
    int w = tid >> 6, l = tid & 63;
    int c = l & 15, g4 = l >> 4;
    int wm = w >> 1, wn = w & 1;
    int bn = blockIdx.x, bm = blockIdx.y;

    f32x4 acc[4][4];
#pragma unroll
    for (int i = 0; i < 4; i++)
#pragma unroll
        for (int j = 0; j < 4; j++) acc[i][j] = (f32x4){0.f, 0.f, 0.f, 0.f};

    const bf16* gB[4];
    gB[0] = Ah + (size_t)bm * 128 * K;
    gB[1] = Bh + (size_t)bn * 128 * K;
    gB[2] = Bl + (size_t)bn * 128 * K;
    gB[3] = ASPLIT ? (Al + (size_t)bm * 128 * K) : gB[0];
    const int NSEG = NBUF * 8;                 // 1KB segments (16 rows) per buffer
    int lr4 = l >> 2, lc4 = l & 3;             // lane -> (row-in-seg, chunk)

    auto STAGE = [&](int kt, int pg) {
#pragma unroll
        for (int sidx = w; sidx < NSEG; sidx += 4) {
            int bsel = sidx >> 3, seg = sidx & 7;
            int r = seg * 16 + lr4;
            int cs = lc4 ^ ((r >> 1) & 3);                     // inverse-swizzled source chunk
            const bf16* g = gB[bsel] + (size_t)r * K + kt + cs * 8;
            async16(g, LDS[pg] + bsel * 8192 + seg * 1024);    // + lane*16 implicit
        }
    };

    STAGE(0, 0);
    __syncthreads();              // tile 0 staged (vmcnt drained by barrier)
    int cur = 0;
    for (int kt = 0; kt < K; kt += 32) {
        if (kt + 32 < K) STAGE(kt + 32, cur ^ 1);   // prefetch in flight under compute

        char* base = LDS[cur];
        char* LAhB = base;
        char* LBhB = base + 8192;
        char* LBlB = base + 16384;
        char* LAlB = base + 24576;                  // deref'd only if ASPLIT

        short8v fah[4], fal[4], fbh[4], fbl[4];
#pragma unroll
        for (int i = 0; i < 4; i++) {
            int row = wm * 64 + i * 16 + c;
            int off = row * 64 + 16 * (g4 ^ ((row >> 1) & 3));
            fah[i] = *(const short8v*)(LAhB + off);
            if (ASPLIT) fal[i] = *(const short8v*)(LAlB + off);
        }
#pragma unroll
        for (int j = 0; j < 4; j++) {
            int row = wn * 64 + j * 16 + c;
            int off = row * 64 + 16 * (g4 ^ ((row >> 1) & 3));
            fbh[j] = *(const short8v*)(LBhB + off);
            fbl[j] = *(const short8v*)(LBlB + off);
        }
#pragma unroll
        for (int i = 0; i < 4; i++)
#pragma unroll
            for (int j = 0; j < 4; j++) {
                f32x4 t = acc[i][j];
                t = mfma16(fah[i], fbl[j], t);
                if (ASPLIT) t = mfma16(fal[i], fbh[j], t);
                t = mfma16(fah[i], fbh[j], t);
                acc[i][j] = t;
            }
        __syncthreads();          // prefetch landed; all reads of LDS[cur] done
        cur ^= 1;
    }

#pragma unroll
    for (int i = 0; i < 4; i++)
#pragma unroll
        for (int j = 0; j < 4; j++) {
            int colg = bn * 128 + wn * 64 + j * 16 + c;
            float bv = bias[colg];
#pragma unroll
            for (int r = 0; r < 4; r++) {
                int rowg = bm * 128 + wm * 64 + i * 16 + g4 * 4 + r;
                float v = acc[i][j][r] + bv;
                if (EPI == 1) {
                    float t = tanhf(0.7978845608028654f * (v + 0.044715f * v * v * v));
                    v = 0.5f * v * (1.0f + t);
                } else if (EPI == 2) {
                    v += res[(size_t)rowg * N + colg];
                }
                if (OUTBF16) Cb[(size_t)rowg * N + colg] = f2bf(v);
                else         Cf[(size_t)rowg * N + colg] = v;
            }
        }
}

// ---------------------------------------------------------------- RoPE (q,k) from bf16 qkv
__global__ __launch_bounds__(256) void rope_kernel(const bf16* __restrict__ qkv,
                                                   bf16* __restrict__ Q, bf16* __restrict__ K) {
    int idx = blockIdx.x * 256 + threadIdx.x;  // BH * T * 32
    int d  = idx & 31;
    int t  = (idx >> 5) & (T_LEN - 1);
    int bh = idx >> 16;
    int b  = bh >> 4;
    int h  = bh & 15;
    size_t row = (size_t)(t * B_SZ + b) * C3 + h * D_HEAD + d;
    float q0 = bf2f(qkv[row]),          q1 = bf2f(qkv[row + 32]);
    float k0 = bf2f(qkv[row + C_DIM]),  k1 = bf2f(qkv[row + C_DIM + 32]);
    q0 *= 0.125f; q1 *= 0.125f;               // D^-0.5
    float theta = exp2f((float)d * (-13.287712379549449f / 32.0f));  // 10000^(-d/32)
    float ang = (float)t * theta;
    float sn, cs;
    sincosf(ang, &sn, &cs);
    size_t ob = ((size_t)bh * T_LEN + t) * D_HEAD + d;
    Q[ob]      = f2bf(cs * q0 - sn * q1);
    Q[ob + 32] = f2bf(cs * q1 + sn * q0);
    K[ob]      = f2bf(cs * k0 - sn * k1);
    K[ob + 32] = f2bf(cs * k1 + sn * k0);
}

// ---------------------------------------------------------------- V transpose: qkv v-part -> Vt (BH, D, T)
// LDS elem(t,d) @ byte t*128 + 16*((d>>3)^((t>>3)&7)) + 2*(d&7): both phases <=2-way banks.
__global__ __launch_bounds__(256) void vt_kernel(const bf16* __restrict__ qkv, bf16* __restrict__ Vt) {
    __shared__ __align__(16) short L[64 * 64];
    char* LB = (char*)L;
    int qt = blockIdx.x, bh = blockIdx.y;
    int b = bh >> 4, h = bh & 15;
    int tid = threadIdx.x;
    int t0 = qt * 64;
#pragma unroll
    for (int e = 0; e < 2; e++) {
        int t = (tid >> 3) + e * 32, dc = tid & 7;
        short8v v = *(const short8v*)(qkv + (size_t)((t0 + t) * B_SZ + b) * C3 + 2 * C_DIM + h * 64 + dc * 8);
        *(short8v*)(LB + t * 128 + 16 * (dc ^ ((t >> 3) & 7))) = v;
    }
    __syncthreads();
    int d = tid & 63, tcb = tid >> 6;   // 16 t per thread
    short8v v0, v1;
#pragma unroll
    for (int i = 0; i < 8; i++) {
        int t = tcb * 16 + i;
        v0[i] = *(const short*)(LB + t * 128 + 16 * ((d >> 3) ^ ((t >> 3) & 7)) + 2 * (d & 7));
    }
#pragma unroll
    for (int i = 0; i < 8; i++) {
        int t = tcb * 16 + 8 + i;
        v1[i] = *(const short*)(LB + t * 128 + 16 * ((d >> 3) ^ ((t >> 3) & 7)) + 2 * (d & 7));
    }
    bf16* op = Vt + ((size_t)bh * 64 + d) * T_LEN + t0 + tcb * 16;
    *(short8v*)(op)     = v0;
    *(short8v*)(op + 8) = v1;
}

// ---------------------------------------------------------------- causal flash attention, bf16 MFMA
// grid (NQT/2, BH), 4 waves. BALANCED PAIRING: block p processes q-tiles {p, NQT-1-p}
// sequentially -> every block does exactly NQT+1=33 KV-iterations (round-10 post-mortem:
// all blocks co-resident, so duration = heaviest block; pairing flattens the triangle).
// T14 PREFETCH: next KV tile's global loads issued right after current ds_write ->
// latency hides under QK^T+softmax+PV (was: issued just before the consuming barrier).
// Per-q-tile instruction sequence unchanged -> output bitwise identical to round 7/10.
// K elem(kv,d): byte kv*128 + 16*((d>>3)^(kv&7)) + 2*(d&7)
// Vt elem(d,kv): byte d*128 + 16*((kv>>3)^(d&7)) + 2*(kv&7)
// Ps elem(q,kv) per wave: byte q*128 + 16*((kv>>3)^(q&7)) + 2*(kv&7)
__global__ __launch_bounds__(256) void attn_kernel(const bf16* __restrict__ Qg, const bf16* __restrict__ Kg,
                                                   const bf16* __restrict__ Vt,
                                                   bf16* __restrict__ Ohi, bf16* __restrict__ Olo) {
    __shared__ __align__(16) short Kl[64 * 64];
    __shared__ __align__(16) short Vl[64 * 64];
    __shared__ __align__(16) short Ps[4 * 16 * 64];
    char* KlB = (char*)Kl; char* VlB = (char*)Vl;
    int bh = blockIdx.y;
    int tid = threadIdx.x;
    int w = tid >> 6, l = tid & 63;
    int c = l & 15, g4 = l >> 4;
    char* PsB = (char*)Ps + w * 2048;
    int skv = tid >> 3, sc8 = tid & 7;      // staging coords
    int b = bh >> 4, h = bh & 15;

    const bf16* Kbase = Kg + (size_t)bh * T_LEN * 64;
    const bf16* Vbase = Vt + (size_t)bh * 64 * T_LEN;

#pragma unroll 1
    for (int ph = 0; ph < 2; ph++) {
        int qt = ph ? (NQT - 1 - blockIdx.x) : blockIdx.x;

        // Q fragments (2 k-steps of 32 over D=64), direct from global
        int q0 = qt * 64 + w * 16;
        const bf16* Qb = Qg + ((size_t)bh * T_LEN + q0 + c) * 64 + g4 * 8;
        short8v qf0 = *(const short8v*)(Qb);
        short8v qf1 = *(const short8v*)(Qb + 32);

        f32x4 oacc[4];
        float m_r[4], l_r[4];
#pragma unroll
        for (int i = 0; i < 4; i++) { oacc[i] = (f32x4){0.f,0.f,0.f,0.f}; m_r[i] = -1e30f; l_r[i] = 0.f; }

        // preload KV tile 0 into regs
        short8v kcur[2], vcur[2];
#pragma unroll
        for (int e = 0; e < 2; e++) {
            int rkv = skv + e * 32;
            kcur[e] = *(const short8v*)(Kbase + (size_t)rkv * 64 + sc8 * 8);
            vcur[e] = *(const short8v*)(Vbase + (size_t)rkv * T_LEN + sc8 * 8);
        }

        for (int kt = 0; kt <= qt; kt++) {
            __syncthreads();   // prev tile's (or prev phase's) LDS reads done
#pragma unroll
            for (int e = 0; e < 2; e++) {
                int rkv = skv + e * 32;
                *(short8v*)(KlB + rkv * 128 + 16 * (sc8 ^ (rkv & 7))) = kcur[e];
                *(short8v*)(VlB + rkv * 128 + 16 * (sc8 ^ (rkv & 7))) = vcur[e];
            }
            __syncthreads();

            if (kt < qt) {     // T14: prefetch next tile under this tile's compute
                int kv1 = (kt + 1) * 64;
#pragma unroll
                for (int e = 0; e < 2; e++) {
                    int rkv = skv + e * 32;
                    kcur[e] = *(const short8v*)(Kbase + (size_t)(kv1 + rkv) * 64 + sc8 * 8);
                    vcur[e] = *(const short8v*)(Vbase + (size_t)rkv * T_LEN + kv1 + sc8 * 8);
                }
            }

            // ---- scores S = Q K^T : 4 kv-frags x 2 d-steps
            f32x4 s[4];
#pragma unroll
            for (int j = 0; j < 4; j++) s[j] = (f32x4){0.f,0.f,0.f,0.f};
#pragma unroll
            for (int j = 0; j < 4; j++) {
                int row = j * 16 + c;
                short8v kb0 = *(const short8v*)(KlB + row * 128 + 16 * ((g4)     ^ (row & 7)));
                short8v kb1 = *(const short8v*)(KlB + row * 128 + 16 * ((4 + g4) ^ (row & 7)));
                s[j] = mfma16(qf0, kb0, s[j]);
                s[j] = mfma16(qf1, kb1, s[j]);
            }
            if (kt == qt) {   // causal mask within diagonal tile
#pragma unroll
                for (int j = 0; j < 4; j++)
#pragma unroll
                    for (int r = 0; r < 4; r++)
                        if (j * 16 + c > w * 16 + g4 * 4 + r) s[j][r] = -1e30f;
            }

            // ---- online softmax (rows r; 16 cols per frag across lanes c)
#pragma unroll
            for (int r = 0; r < 4; r++) {
                float tm = fmaxf(fmaxf(s[0][r], s[1][r]), fmaxf(s[2][r], s[3][r]));
#pragma unroll
                for (int mk = 1; mk < 16; mk <<= 1) tm = fmaxf(tm, __shfl_xor(tm, mk, 64));
                float mnew = fmaxf(m_r[r], tm);
                float sc = __expf(m_r[r] - mnew);
                int q = g4 * 4 + r;
                float rs = 0.f;
#pragma unroll
                for (int j = 0; j < 4; j++) {
                    float p = __expf(s[j][r] - mnew);
                    rs += p;
                    *(short*)(PsB + q * 128 + 16 * ((2 * j + (c >> 3)) ^ (q & 7)) + 2 * (c & 7)) = f2bfs(p);
                }
#pragma unroll
                for (int mk = 1; mk < 16; mk <<= 1) rs += __shfl_xor(rs, mk, 64);
                l_r[r] = l_r[r] * sc + rs;
                m_r[r] = mnew;
#pragma unroll
                for (int jd = 0; jd < 4; jd++) oacc[jd][r] *= sc;
            }
            __syncthreads();   // Ps visible (cross-lane); K/V reads done before next overwrite

            // ---- O += P V : A = P frag (q=c rows), B = Vt frag
#pragma unroll
            for (int ks = 0; ks < 2; ks++) {
                short8v pa = *(const short8v*)(PsB + c * 128 + 16 * ((ks * 4 + g4) ^ (c & 7)));
#pragma unroll
                for (int jd = 0; jd < 4; jd++) {
                    int row = jd * 16 + c;
                    short8v vb = *(const short8v*)(VlB + row * 128 + 16 * ((ks * 4 + g4) ^ (row & 7)));
                    oacc[jd] = mfma16(pa, vb, oacc[jd]);
                }
            }
        }

        // ---- epilogue: divide by l, write hi/lo bf16 at (t*B+b, h*64+d)
#pragma unroll
        for (int r = 0; r < 4; r++) {
            float inv = 1.0f / l_r[r];
            int t = qt * 64 + w * 16 + g4 * 4 + r;
            size_t rb = (size_t)(t * B_SZ + b) * C_DIM + h * 64;
#pragma unroll
            for (int jd = 0; jd < 4; jd++) {
                float v = oacc[jd][r] * inv;
                short hs, ls;
                split2(v, hs, ls);
                *(short*)&Ohi[rb + jd * 16 + c] = hs;
                *(short*)&Olo[rb + jd * 16 + c] = ls;
            }
        }
    }
}

// ---------------------------------------------------------------- launcher
extern "C" void kernel_launch(void* const* d_in, const int* in_sizes, int n_in,
                              void* d_out, int out_size, void* d_ws, size_t ws_size,
                              hipStream_t stream) {
    (void)in_sizes; (void)n_in; (void)out_size; (void)ws_size;
    const float* x     = (const float*)d_in[0];
    const float* in_w  = (const float*)d_in[1];
    const float* in_b  = (const float*)d_in[2];
    const float* out_w = (const float*)d_in[3];
    const float* out_b = (const float*)d_in[4];
    const float* ln1_g = (const float*)d_in[5];
    const float* ln1_b = (const float*)d_in[6];
    const float* ln2_g = (const float*)d_in[7];
    const float* ln2_b = (const float*)d_in[8];
    const float* w1    = (const float*)d_in[9];
    const float* b1    = (const float*)d_in[10];
    const float* w2    = (const float*)d_in[11];
    const float* b2    = (const float*)d_in[12];
    float* out = (float*)d_out;
    char* ws = (char*)d_ws;

    const size_t MB = 1 << 20;
    // persistent weight splits [0,48MB)
    bf16* inw_h  = (bf16*)(ws + 0 * MB);
    bf16* inw_l  = (bf16*)(ws + 6 * MB);
    bf16* outw_h = (bf16*)(ws + 12 * MB);
    bf16* outw_l = (bf16*)(ws + 14 * MB);
    bf16* w1_h   = (bf16*)(ws + 16 * MB);
    bf16* w1_l   = (bf16*)(ws + 24 * MB);
    bf16* w2_h   = (bf16*)(ws + 32 * MB);
    bf16* w2_l   = (bf16*)(ws + 40 * MB);
    // activations (with lifetime reuse)
    bf16* ln1o_h = (bf16*)(ws + 48 * MB);   // dead after QKV gemm
    bf16* ln1o_l = (bf16*)(ws + 56 * MB);
    bf16* qkv    = (bf16*)(ws + 64 * MB);   // 24MB, dead after rope/vt
    bf16* Qg     = (bf16*)(ws + 88 * MB);   // dead after attn
    bf16* Kg     = (bf16*)(ws + 96 * MB);
    bf16* Vt     = (bf16*)(ws + 104 * MB);
    bf16* O_h    = (bf16*)(ws + 48 * MB);   // reuse ln1o slot
    bf16* O_l    = (bf16*)(ws + 56 * MB);
    float* x2    = (float*)(ws + 112 * MB); // 16MB, live to end
    bf16* h2_h   = (bf16*)(ws + 64 * MB);   // reuse qkv slot
    bf16* h2_l   = (bf16*)(ws + 72 * MB);
    bf16* f1     = (bf16*)(ws + 80 * MB);   // 32MB, overlays dead Q/K/Vt

    // 0. weight hi/lo splits
    split_kernel<<<3072, 256, 0, stream>>>(in_w, inw_h, inw_l);
    split_kernel<<<1024, 256, 0, stream>>>(out_w, outw_h, outw_l);
    split_kernel<<<4096, 256, 0, stream>>>(w1, w1_h, w1_l);
    split_kernel<<<4096, 256, 0, stream>>>(w2, w2_h, w2_l);
    // 1. LN1 -> split
    ln_split_kernel<<<NT, 256, 0, stream>>>(x, ln1_g, ln1_b, ln1o_h, ln1o_l);
    // 2. QKV projection (split A,B; bf16 out)
    gemm_bf16<0, true, true><<<dim3(C3 / 128, NT / 128), 256, 0, stream>>>(
        ln1o_h, ln1o_l, inw_h, inw_l, in_b, nullptr, nullptr, qkv, C3, C_DIM);
    // 3. RoPE q,k + 4. V transpose
    rope_kernel<<<(BH * T_LEN * 32) / 256, 256, 0, stream>>>(qkv, Qg, Kg);
    vt_kernel<<<dim3(T_LEN / 64, BH), 256, 0, stream>>>(qkv, Vt);
    // 5. causal flash attention (bf16 MFMA), balanced-pair blocks, O as hi/lo split
    attn_kernel<<<dim3(NQT / 2, BH), 256, 0, stream>>>(Qg, Kg, Vt, O_h, O_l);
    // 6. output projection + residual(x) -> x2 fp32
    gemm_bf16<2, true, false><<<dim3(C_DIM / 128, NT / 128), 256, 0, stream>>>(
        O_h, O_l, outw_h, outw_l, out_b, x, x2, nullptr, C_DIM, C_DIM);
    // 7. LN2 -> split
    ln_split_kernel<<<NT, 256, 0, stream>>>(x2, ln2_g, ln2_b, h2_h, h2_l);
    // 8. FFN up + GELU -> f1 bf16
    gemm_bf16<1, true, true><<<dim3(F_DIM / 128, NT / 128), 256, 0, stream>>>(
        h2_h, h2_l, w1_h, w1_l, b1, nullptr, nullptr, f1, F_DIM, C_DIM);
    // 9. FFN down + residual(x2) -> out fp32 (A direct bf16, B split)
    gemm_bf16<2, false, false><<<dim3(C_DIM / 128, NT / 128), 256, 0, stream>>>(
        f1, nullptr, w2_h, w2_l, b2, x2, out, nullptr, C_DIM, F_DIM);
}